// Round 7
// baseline (223.733 us; speedup 1.0000x reference)
//
#include <hip/hip_runtime.h>
#include <math.h>

#define D_IN   256
#define D_E    64
#define N_SUP  16384
#define NQ     256
#define KSEL   32
#define RTOLC  1e-5f
#define ATOLC  1e-5f
#define INV_T  10.0f    // 1/TEMPERATURE

#define CHUNK  1024     // support rows per phase-A block
#define NCH    16       // support chunks
#define QG     8        // queries per phase-A block (= waves)
#define NQG    32       // query groups

typedef unsigned long long ull;

__device__ __forceinline__ float gelu_exact(float x) {
    return 0.5f * x * (1.0f + erff(x * 0.70710678118654752440f));
}

// ---------------------------------------------------------------------------
// Embed: 260 blocks x 512 threads (8 waves), 64 rows/block (lane = row), wave
// w computes features [8w, 8w+8). x chunk transposed in LDS (as R6); weights
// now ALSO LDS-staged, transposed on the fly (BW[k][f], pad 68) -> per k:
// 1 ds_read_b32 (x) + 2 broadcast ds_read_b128 (w) + 8 FMA. No s_load streams,
// no prep kernel. FMA order identical to R6 -> absmax 0.
__global__ __launch_bounds__(512, 6) void embed_kernel(
    const float* __restrict__ sx, const float* __restrict__ x,
    const float* __restrict__ W1, const float* __restrict__ b1,
    const float* __restrict__ W2, const float* __restrict__ b2,
    const float* __restrict__ W3, const float* __restrict__ b3,
    float* __restrict__ s_emb, float* __restrict__ s_norm,
    float* __restrict__ q_emb, float* __restrict__ q_norm)
{
    __shared__ float xcB[64][65];    // x chunk [k][row]; reused as hB [f][row]
    __shared__ float hA[64][65];     // layer-1 out [f][row]
    __shared__ float BW[64 * 68];    // W chunk transposed [k][f], pad 68
    __shared__ float nsum[64][9];

    const int tid  = threadIdx.x;
    const int lane = tid & 63;
    const int wv   = tid >> 6;
    const int f0   = __builtin_amdgcn_readfirstlane(wv * 8);
    const bool isq = blockIdx.x >= (N_SUP / 64);
    const float* src = isq ? (x + (size_t)(blockIdx.x - N_SUP / 64) * 64 * D_IN)
                           : (sx + (size_t)blockIdx.x * 64 * D_IN);

    // ---- layer 1: 4 k-chunks of 64
    float acc[8];
    #pragma unroll
    for (int i = 0; i < 8; ++i) acc[i] = b1[f0 + i];

    for (int kc = 0; kc < 4; ++kc) {
        __syncthreads();                       // prev chunk fully consumed
        // stage x chunk transposed (coalesced float4 loads)
        #pragma unroll
        for (int i = 0; i < 2; ++i) {
            int g   = i * 512 + tid;           // float4 id in [0,1024)
            int row = g >> 4;
            int c4  = g & 15;
            float4 v = *reinterpret_cast<const float4*>(
                src + (size_t)row * D_IN + kc * 64 + c4 * 4);
            xcB[c4 * 4 + 0][row] = v.x; xcB[c4 * 4 + 1][row] = v.y;
            xcB[c4 * 4 + 2][row] = v.z; xcB[c4 * 4 + 3][row] = v.w;
        }
        // stage W1 chunk transposed: BW[k][f] = W1[f][kc*64+k]
        #pragma unroll
        for (int i = 0; i < 2; ++i) {
            int f  = (tid >> 4) + 32 * i;
            int c4 = tid & 15;
            float4 w = *reinterpret_cast<const float4*>(
                W1 + (size_t)f * D_IN + kc * 64 + c4 * 4);
            BW[(c4 * 4 + 0) * 68 + f] = w.x; BW[(c4 * 4 + 1) * 68 + f] = w.y;
            BW[(c4 * 4 + 2) * 68 + f] = w.z; BW[(c4 * 4 + 3) * 68 + f] = w.w;
        }
        __syncthreads();
        #pragma unroll 8
        for (int k = 0; k < 64; ++k) {
            float xk = xcB[k][lane];
            const float* wk = &BW[k * 68 + f0];          // broadcast b128 x2
            float4 w0 = *reinterpret_cast<const float4*>(wk);
            float4 w1 = *reinterpret_cast<const float4*>(wk + 4);
            acc[0] = fmaf(w0.x, xk, acc[0]); acc[1] = fmaf(w0.y, xk, acc[1]);
            acc[2] = fmaf(w0.z, xk, acc[2]); acc[3] = fmaf(w0.w, xk, acc[3]);
            acc[4] = fmaf(w1.x, xk, acc[4]); acc[5] = fmaf(w1.y, xk, acc[5]);
            acc[6] = fmaf(w1.z, xk, acc[6]); acc[7] = fmaf(w1.w, xk, acc[7]);
        }
    }
    __syncthreads();                            // last x-chunk reads done
    #pragma unroll
    for (int i = 0; i < 8; ++i) hA[f0 + i][lane] = gelu_exact(acc[i]);

    // ---- layer 2: stage W2 transposed, read hA, write hB into xcB
    {
        #pragma unroll
        for (int i = 0; i < 2; ++i) {
            int f  = (tid >> 4) + 32 * i;
            int c4 = tid & 15;
            float4 w = *reinterpret_cast<const float4*>(W2 + (size_t)f * D_E + c4 * 4);
            BW[(c4 * 4 + 0) * 68 + f] = w.x; BW[(c4 * 4 + 1) * 68 + f] = w.y;
            BW[(c4 * 4 + 2) * 68 + f] = w.z; BW[(c4 * 4 + 3) * 68 + f] = w.w;
        }
    }
    __syncthreads();
    float a2[8];
    #pragma unroll
    for (int i = 0; i < 8; ++i) a2[i] = b2[f0 + i];
    #pragma unroll 8
    for (int k = 0; k < D_E; ++k) {
        float hk = hA[k][lane];
        const float* wk = &BW[k * 68 + f0];
        float4 w0 = *reinterpret_cast<const float4*>(wk);
        float4 w1 = *reinterpret_cast<const float4*>(wk + 4);
        a2[0] = fmaf(w0.x, hk, a2[0]); a2[1] = fmaf(w0.y, hk, a2[1]);
        a2[2] = fmaf(w0.z, hk, a2[2]); a2[3] = fmaf(w0.w, hk, a2[3]);
        a2[4] = fmaf(w1.x, hk, a2[4]); a2[5] = fmaf(w1.y, hk, a2[5]);
        a2[6] = fmaf(w1.z, hk, a2[6]); a2[7] = fmaf(w1.w, hk, a2[7]);
    }
    __syncthreads();                            // BW reads done; hA reads done
    #pragma unroll
    for (int i = 0; i < 8; ++i) xcB[f0 + i][lane] = gelu_exact(a2[i]);   // hB

    // ---- layer 3: stage W3, read hB (xcB), sigmoid + norm
    {
        #pragma unroll
        for (int i = 0; i < 2; ++i) {
            int f  = (tid >> 4) + 32 * i;
            int c4 = tid & 15;
            float4 w = *reinterpret_cast<const float4*>(W3 + (size_t)f * D_E + c4 * 4);
            BW[(c4 * 4 + 0) * 68 + f] = w.x; BW[(c4 * 4 + 1) * 68 + f] = w.y;
            BW[(c4 * 4 + 2) * 68 + f] = w.z; BW[(c4 * 4 + 3) * 68 + f] = w.w;
        }
    }
    __syncthreads();
    float a3[8];
    #pragma unroll
    for (int i = 0; i < 8; ++i) a3[i] = b3[f0 + i];
    #pragma unroll 8
    for (int k = 0; k < D_E; ++k) {
        float hk = xcB[k][lane];
        const float* wk = &BW[k * 68 + f0];
        float4 w0 = *reinterpret_cast<const float4*>(wk);
        float4 w1 = *reinterpret_cast<const float4*>(wk + 4);
        a3[0] = fmaf(w0.x, hk, a3[0]); a3[1] = fmaf(w0.y, hk, a3[1]);
        a3[2] = fmaf(w0.z, hk, a3[2]); a3[3] = fmaf(w0.w, hk, a3[3]);
        a3[4] = fmaf(w1.x, hk, a3[4]); a3[5] = fmaf(w1.y, hk, a3[5]);
        a3[6] = fmaf(w1.z, hk, a3[6]); a3[7] = fmaf(w1.w, hk, a3[7]);
    }
    float e[8];
    float np = 0.0f;
    #pragma unroll
    for (int i = 0; i < 8; ++i) {
        e[i] = 1.0f / (1.0f + expf(-a3[i]));
        np = fmaf(e[i], e[i], np);
    }

    const int rowl = isq ? (blockIdx.x - N_SUP / 64) * 64 + lane
                         : blockIdx.x * 64 + lane;
    float* E   = isq ? q_emb  : s_emb;
    float* Nrm = isq ? q_norm : s_norm;
    float* erow = E + (size_t)rowl * D_E + f0;
    *reinterpret_cast<float4*>(erow)     = make_float4(e[0], e[1], e[2], e[3]);
    *reinterpret_cast<float4*>(erow + 4) = make_float4(e[4], e[5], e[6], e[7]);

    nsum[lane][wv] = np;
    __syncthreads();
    if (wv == 0) {
        float s = 0.0f;
        #pragma unroll
        for (int w = 0; w < 8; ++w) s += nsum[lane][w];
        Nrm[rowl] = s;
    }
}

// ---------------------------------------------------------------------------
// Phase A: grid 512 (qg = b>>4, sc = b&15), 512 threads.
// Dist phase: 16 stages of 64 rows staged coalesced into LDS (pad 68). Lane
// (q = lane>>3, rsub = lane&7) of wave w computes the dot of tile row
// w*8+rsub with query q -- tile rows read as 8-way broadcasts (once total),
// query row held in 16 float4 VGPRs. FMA chain k-ascending = identical d2
// bits to R6. Selection (unchanged from R6): wave = query, sort-16 + 32
// argmin rounds, labels fetched in parallel, cand = (d2bits<<32)|labelbits.
__global__ __launch_bounds__(512, 4) void knn_phaseA(
    const float* __restrict__ s_emb, const float* __restrict__ s_norm,
    const float* __restrict__ q_emb, const float* __restrict__ q_norm,
    const float* __restrict__ labels, ull* __restrict__ cand)
{
    __shared__ float tile[64 * 68];             // 17.4 KB
    __shared__ float d2l[QG][1032];             // 33 KB, pad 1032: 2-way max
    __shared__ ull   win_l[QG][KSEL];           // 2 KB

    const int tid  = threadIdx.x;
    const int lane = tid & 63;
    const int wid  = tid >> 6;
    const int qg   = blockIdx.x >> 4;
    const int sc   = blockIdx.x & 15;

    // per-lane query row in registers (8 lanes share a query)
    const int  ql   = lane >> 3;                // query within group
    const int  rsub = lane & 7;
    const float* qrow = q_emb + (size_t)(qg * QG + ql) * D_E;
    float4 qv[16];
    #pragma unroll
    for (int c = 0; c < 16; ++c)
        qv[c] = *reinterpret_cast<const float4*>(qrow + c * 4);
    const float qn = q_norm[qg * QG + ql];

    for (int s = 0; s < 16; ++s) {
        __syncthreads();
        #pragma unroll
        for (int i = 0; i < 2; ++i) {
            int g   = i * 512 + tid;            // float4 id in [0,1024)
            int row = g >> 4, c4 = g & 15;
            float4 v = *reinterpret_cast<const float4*>(
                s_emb + (size_t)(sc * CHUNK + s * 64 + row) * D_E + c4 * 4);
            *reinterpret_cast<float4*>(&tile[row * 68 + c4 * 4]) = v;
        }
        __syncthreads();

        const int rloc = wid * 8 + rsub;        // row within tile
        const float* tr = &tile[rloc * 68];
        float a = 0.0f;
        #pragma unroll
        for (int c = 0; c < 16; ++c) {
            float4 sv = *reinterpret_cast<const float4*>(tr + c * 4);
            a = fmaf(qv[c].x, sv.x, a);
            a = fmaf(qv[c].y, sv.y, a);
            a = fmaf(qv[c].z, sv.z, a);
            a = fmaf(qv[c].w, sv.w, a);
        }
        const int grow = sc * CHUNK + s * 64 + rloc;
        float d2 = fmaxf(qn + s_norm[grow] - 2.0f * a, 0.0f);
        if (d2 < 1e-3f) {
            // possible isclose duplicate; true mask needs d2 <= 2.6e-8, fp32
            // error on d2 <= ~1e-5 -> 100x margin, branch ~never taken
            bool close = true;
            #pragma unroll 8
            for (int k = 0; k < D_E; ++k) {
                float svk = tr[k];
                float qk  = reinterpret_cast<const float*>(qv)[k];
                close = close && (fabsf(qk - svk) <= (ATOLC + RTOLC * fabsf(svk)));
            }
            if (close) d2 = INFINITY;
        }
        d2l[ql][s * 64 + rloc] = d2;
    }
    __syncthreads();                            // cross-wave d2 visibility

    // ---- per-wave top-32 for query `wid` (identical to R6)
    ull sk[16];
    #pragma unroll
    for (int j = 0; j < 16; ++j) {
        float d2 = d2l[wid][j * 64 + lane];
        sk[j] = ((ull)__float_as_uint(d2) << 10) | (unsigned)(j * 64 + lane);
    }

    #pragma unroll
    for (int k = 2; k <= 16; k <<= 1) {
        #pragma unroll
        for (int j = k >> 1; j > 0; j >>= 1) {
            #pragma unroll
            for (int i = 0; i < 16; ++i) {
                int ixj = i ^ j;
                if (ixj > i) {
                    if ((i & k) == 0) {
                        ull a_ = sk[i], b_ = sk[ixj];
                        bool c_ = b_ < a_;
                        sk[i] = c_ ? b_ : a_; sk[ixj] = c_ ? a_ : b_;
                    } else {
                        ull a_ = sk[i], b_ = sk[ixj];
                        bool c_ = a_ < b_;
                        sk[i] = c_ ? b_ : a_; sk[ixj] = c_ ? a_ : b_;
                    }
                }
            }
        }
    }

    ull lkey = sk[0];
    for (int it = 0; it < KSEL; ++it) {
        ull m = lkey;
        #pragma unroll
        for (int off = 1; off < 64; off <<= 1) {
            ull o = __shfl_xor(m, off);
            m = o < m ? o : m;
        }
        if (lane == it) win_l[wid][it] = m;
        if (lkey == m) {                        // unique winner lane
            #pragma unroll
            for (int j = 0; j < 15; ++j) sk[j] = sk[j + 1];
            sk[15] = ~0ull;
            lkey = sk[0];
        }
    }

    if (lane < KSEL) {
        ull m = win_l[wid][lane];
        unsigned gidx = (unsigned)(sc * CHUNK) + (unsigned)(m & 1023u);
        float lab = labels[gidx];
        ull* dst = cand + ((size_t)(qg * QG + wid) * NCH + sc) * KSEL;
        dst[lane] = ((ull)(unsigned)(m >> 10) << 32) | (ull)__float_as_uint(lab);
    }
}

// ---------------------------------------------------------------------------
// Phase B: unchanged from R6 (absmax 0). Wave per query; lanes 0..15 merge
// the 16 sorted chunk lists; labels ride in the candidate payload.
__global__ __launch_bounds__(256) void knn_phaseB(
    const ull* __restrict__ cand, float* __restrict__ out)
{
    const int lane = threadIdx.x & 63;
    const int wid  = threadIdx.x >> 6;
    const int q    = blockIdx.x * 4 + wid;

    const bool act = lane < NCH;
    const ull* lst = cand + ((size_t)q * NCH + (lane & 15)) * KSEL;
    int ptr = 0;
    ull cur = act ? lst[0] : ~0ull;

    float d0 = 0.0f, sw = 0.0f, sl = 0.0f;
    for (int it = 0; it < KSEL; ++it) {
        unsigned mv = (unsigned)(cur >> 32);
        unsigned ml = (unsigned)cur;
        #pragma unroll
        for (int off = 1; off < 16; off <<= 1) {
            unsigned ov = __shfl_xor(mv, off);
            unsigned ol = __shfl_xor(ml, off);
            bool take = (ov < mv) || (ov == mv && (lane & off));
            mv = take ? ov : mv;
            ml = take ? ol : ml;
        }
        ull b = __ballot(act && (unsigned)(cur >> 32) == mv);
        int wl = (int)(__ffsll((long long)b) - 1);
        if (lane == wl) {
            ++ptr;
            cur = (ptr < KSEL) ? lst[ptr] : ~0ull;
        }
        if (lane == 0) {
            float d = sqrtf(__uint_as_float(mv));
            if (it == 0) d0 = d;
            float w = expf((d0 - d) * INV_T);
            sw += w;
            sl += w * __uint_as_float(ml);
        }
    }
    if (lane == 0) out[q] = sl / sw;
}

// ---------------------------------------------------------------------------
extern "C" void kernel_launch(void* const* d_in, const int* in_sizes, int n_in,
                              void* d_out, int out_size, void* d_ws, size_t ws_size,
                              hipStream_t stream) {
    const float* x      = (const float*)d_in[0];   // [256,256]
    const float* sx     = (const float*)d_in[1];   // [16384,256]
    const float* labels = (const float*)d_in[2];   // [16384,1]
    const float* W1     = (const float*)d_in[3];   // [64,256]
    const float* b1     = (const float*)d_in[4];
    const float* W2     = (const float*)d_in[5];   // [64,64]
    const float* b2     = (const float*)d_in[6];
    const float* W3     = (const float*)d_in[7];   // [64,64]
    const float* b3     = (const float*)d_in[8];
    float* out = (float*)d_out;

    float* ws     = (float*)d_ws;
    float* s_emb  = ws;                            // 16384*64
    float* s_norm = s_emb + N_SUP * D_E;           // 16384
    float* q_emb  = s_norm + N_SUP;                // 256*64
    float* q_norm = q_emb + NQ * D_E;              // 256
    ull*   cand   = (ull*)(q_norm + NQ);           // 256*16*32 ull (8B aligned)

    embed_kernel<<<(N_SUP + NQ) / 64, 512, 0, stream>>>(
        sx, x, W1, b1, W2, b2, W3, b3, s_emb, s_norm, q_emb, q_norm);
    knn_phaseA<<<NQG * NCH, 512, 0, stream>>>(s_emb, s_norm, q_emb, q_norm,
                                              labels, cand);
    knn_phaseB<<<NQ / 4, 256, 0, stream>>>(cand, out);
}

// Round 8
// 152.072 us; speedup vs baseline: 1.4712x; 1.4712x over previous
//
#include <hip/hip_runtime.h>
#include <math.h>

#define D_IN   256
#define D_E    64
#define N_SUP  16384
#define NQ     256
#define KSEL   32
#define RTOLC  1e-5f
#define ATOLC  1e-5f
#define INV_T  10.0f    // 1/TEMPERATURE

#define CHUNK  1024     // support rows per phase-A block
#define NCH    16       // support chunks
#define QG     8        // queries per phase-A block (= waves)
#define NQG    32       // query groups

typedef unsigned long long ull;

__device__ __forceinline__ float gelu_exact(float x) {
    return 0.5f * x * (1.0f + erff(x * 0.70710678118654752440f));
}

// ---------------------------------------------------------------------------
// Prep: transpose weights so embed's k-loop does one uniform s_load per k.
__global__ __launch_bounds__(256) void prep_w(
    const float* __restrict__ W1, const float* __restrict__ W2,
    const float* __restrict__ W3,
    float* __restrict__ W1T, float* __restrict__ W2T, float* __restrict__ W3T)
{
    const int t = blockIdx.x * 256 + threadIdx.x;
    const int stride = gridDim.x * 256;
    for (int o = t; o < D_E * D_IN; o += stride) {
        int f = o >> 8, k = o & 255;
        W1T[k * D_E + f] = W1[o];
    }
    for (int o = t; o < D_E * D_E; o += stride) {
        int f = o >> 6, k = o & 63;
        W2T[k * D_E + f] = W2[o];
        W3T[k * D_E + f] = W3[o];
    }
}

// ---------------------------------------------------------------------------
// Embed: 260 blocks x 512 threads (8 waves), 64 rows/block (lane = row), wave
// w computes features [8w, 8w+8). Per k: 1 conflict-free ds_read_b32 (x, from
// transposed LDS chunk) + 1 wave-uniform s_load_dwordx8 (W*T row, scalar pipe)
// + 8 FMA. x chunks double-buffered; x reads batched 8-wide so lgkm waits
// amortize. FMA chain k-ascending (same as R5/R6) -> absmax 0.
__global__ __launch_bounds__(512, 2) void embed_kernel(
    const float* __restrict__ sx, const float* __restrict__ x,
    const float* __restrict__ W1T, const float* __restrict__ b1,
    const float* __restrict__ W2T, const float* __restrict__ b2,
    const float* __restrict__ W3T, const float* __restrict__ b3,
    float* __restrict__ s_emb, float* __restrict__ s_norm,
    float* __restrict__ q_emb, float* __restrict__ q_norm)
{
    __shared__ float xc[2][64][65];   // double-buffered x chunk [k][row], 33 KB
    __shared__ float hA[64][65];      // hidden [f][row]
    __shared__ float nsum[64][9];

    const int tid  = threadIdx.x;
    const int lane = tid & 63;
    const int wv   = tid >> 6;
    const int f0   = __builtin_amdgcn_readfirstlane(wv * 8);
    const bool isq = blockIdx.x >= (N_SUP / 64);
    const float* src = isq ? (x + (size_t)(blockIdx.x - N_SUP / 64) * 64 * D_IN)
                           : (sx + (size_t)blockIdx.x * 64 * D_IN);

    // stage one 64-k chunk of x transposed into xc[buf]
    #define STAGE_X(kc_, buf_)                                                  \
        {                                                                       \
            _Pragma("unroll")                                                   \
            for (int i = 0; i < 2; ++i) {                                       \
                int g   = i * 512 + tid;                                        \
                int row = g >> 4, c4 = g & 15;                                  \
                float4 v = *reinterpret_cast<const float4*>(                    \
                    src + (size_t)row * D_IN + (kc_) * 64 + c4 * 4);            \
                xc[buf_][c4 * 4 + 0][row] = v.x;                                \
                xc[buf_][c4 * 4 + 1][row] = v.y;                                \
                xc[buf_][c4 * 4 + 2][row] = v.z;                                \
                xc[buf_][c4 * 4 + 3][row] = v.w;                                \
            }                                                                   \
        }

    STAGE_X(0, 0);
    __syncthreads();

    // ---- layer 1: 4 k-chunks of 64, k ascending
    float acc[8];
    #pragma unroll
    for (int i = 0; i < 8; ++i) acc[i] = b1[f0 + i];

    for (int kc = 0; kc < 4; ++kc) {
        if (kc < 3) STAGE_X(kc + 1, (kc + 1) & 1);
        const int buf = kc & 1;
        const float* wbase = W1T + (size_t)(kc * 64) * D_E + f0;
        #pragma unroll
        for (int k8 = 0; k8 < 64; k8 += 8) {
            float xk[8];
            #pragma unroll
            for (int j = 0; j < 8; ++j) xk[j] = xc[buf][k8 + j][lane];
            #pragma unroll
            for (int j = 0; j < 8; ++j) {
                const float* wk = wbase + (k8 + j) * D_E;   // uniform -> s_load x8
                #pragma unroll
                for (int f = 0; f < 8; ++f) acc[f] = fmaf(wk[f], xk[j], acc[f]);
            }
        }
        __syncthreads();
    }
    #pragma unroll
    for (int i = 0; i < 8; ++i) hA[f0 + i][lane] = gelu_exact(acc[i]);
    __syncthreads();

    // ---- layer 2: read hA, write hB into xc[0]
    float a2[8];
    #pragma unroll
    for (int i = 0; i < 8; ++i) a2[i] = b2[f0 + i];
    #pragma unroll
    for (int k8 = 0; k8 < 64; k8 += 8) {
        float xk[8];
        #pragma unroll
        for (int j = 0; j < 8; ++j) xk[j] = hA[k8 + j][lane];
        #pragma unroll
        for (int j = 0; j < 8; ++j) {
            const float* wk = W2T + (k8 + j) * D_E + f0;    // uniform
            #pragma unroll
            for (int f = 0; f < 8; ++f) a2[f] = fmaf(wk[f], xk[j], a2[f]);
        }
    }
    #pragma unroll
    for (int i = 0; i < 8; ++i) xc[0][f0 + i][lane] = gelu_exact(a2[i]);  // hB
    __syncthreads();

    // ---- layer 3 + sigmoid + norm
    float a3[8];
    #pragma unroll
    for (int i = 0; i < 8; ++i) a3[i] = b3[f0 + i];
    #pragma unroll
    for (int k8 = 0; k8 < 64; k8 += 8) {
        float xk[8];
        #pragma unroll
        for (int j = 0; j < 8; ++j) xk[j] = xc[0][k8 + j][lane];
        #pragma unroll
        for (int j = 0; j < 8; ++j) {
            const float* wk = W3T + (k8 + j) * D_E + f0;    // uniform
            #pragma unroll
            for (int f = 0; f < 8; ++f) a3[f] = fmaf(wk[f], xk[j], a3[f]);
        }
    }
    float e[8];
    float np = 0.0f;
    #pragma unroll
    for (int i = 0; i < 8; ++i) {
        e[i] = 1.0f / (1.0f + expf(-a3[i]));
        np = fmaf(e[i], e[i], np);
    }

    const int rowl = isq ? (blockIdx.x - N_SUP / 64) * 64 + lane
                         : blockIdx.x * 64 + lane;
    float* E   = isq ? q_emb  : s_emb;
    float* Nrm = isq ? q_norm : s_norm;
    float* erow = E + (size_t)rowl * D_E + f0;
    *reinterpret_cast<float4*>(erow)     = make_float4(e[0], e[1], e[2], e[3]);
    *reinterpret_cast<float4*>(erow + 4) = make_float4(e[4], e[5], e[6], e[7]);

    nsum[lane][wv] = np;
    __syncthreads();
    if (wv == 0) {
        float s = 0.0f;
        #pragma unroll
        for (int w = 0; w < 8; ++w) s += nsum[lane][w];
        Nrm[rowl] = s;
    }
    #undef STAGE_X
}

// ---------------------------------------------------------------------------
// Phase A: grid 512 (qg = b>>4, sc = b&15), 512 threads.
// Dist phase: 16 stages of 64 rows staged coalesced into LDS (pad 68,
// conflict-free). Lane (q = lane>>3, rsub = lane&7) of wave w dots tile row
// w*8+rsub with query q -- tile rows read as 8-way broadcasts, query row in
// 16 float4 VGPRs with ONLY static indexing (the R7 regression was runtime
// indexing in the isclose branch demoting qv to scratch: 342 MB FETCH).
// The cold isclose branch re-reads q from GLOBAL instead. FMA k-ascending =
// identical d2 bits. Selection identical to R6: sort-16 + 32 argmin rounds.
__global__ __launch_bounds__(512, 4) void knn_phaseA(
    const float* __restrict__ s_emb, const float* __restrict__ s_norm,
    const float* __restrict__ q_emb, const float* __restrict__ q_norm,
    const float* __restrict__ labels, ull* __restrict__ cand)
{
    __shared__ float tile[64 * 68];             // 17.4 KB
    __shared__ float d2l[QG][1032];             // 33 KB, pad 1032
    __shared__ ull   win_l[QG][KSEL];           // 2 KB

    const int tid  = threadIdx.x;
    const int lane = tid & 63;
    const int wid  = tid >> 6;
    const int qg   = blockIdx.x >> 4;
    const int sc   = blockIdx.x & 15;

    // per-lane query row in registers (8 lanes share a query); STATIC indexing only
    const int  ql   = lane >> 3;                // query within group
    const int  rsub = lane & 7;
    const float* qrow = q_emb + (size_t)(qg * QG + ql) * D_E;
    float4 qv[16];
    #pragma unroll
    for (int c = 0; c < 16; ++c)
        qv[c] = *reinterpret_cast<const float4*>(qrow + c * 4);
    const float qn = q_norm[qg * QG + ql];

    for (int s = 0; s < 16; ++s) {
        __syncthreads();
        #pragma unroll
        for (int i = 0; i < 2; ++i) {
            int g   = i * 512 + tid;            // float4 id in [0,1024)
            int row = g >> 4, c4 = g & 15;
            float4 v = *reinterpret_cast<const float4*>(
                s_emb + (size_t)(sc * CHUNK + s * 64 + row) * D_E + c4 * 4);
            *reinterpret_cast<float4*>(&tile[row * 68 + c4 * 4]) = v;
        }
        __syncthreads();

        const int rloc = wid * 8 + rsub;        // row within tile
        const float* tr = &tile[rloc * 68];
        float a = 0.0f;
        #pragma unroll
        for (int c = 0; c < 16; ++c) {
            float4 sv = *reinterpret_cast<const float4*>(tr + c * 4);
            a = fmaf(qv[c].x, sv.x, a);
            a = fmaf(qv[c].y, sv.y, a);
            a = fmaf(qv[c].z, sv.z, a);
            a = fmaf(qv[c].w, sv.w, a);
        }
        const int grow = sc * CHUNK + s * 64 + rloc;
        float d2 = fmaxf(qn + s_norm[grow] - 2.0f * a, 0.0f);
        if (d2 < 1e-3f) {
            // possible isclose duplicate; true mask needs d2 <= 2.6e-8, fp32
            // error on d2 <= ~1e-5 -> 100x margin, ~never taken. q re-read from
            // GLOBAL (cold) so qv stays statically-indexed registers.
            bool close = true;
            for (int k = 0; k < D_E; ++k) {
                float svk = tr[k];
                close = close && (fabsf(qrow[k] - svk) <= (ATOLC + RTOLC * fabsf(svk)));
            }
            if (close) d2 = INFINITY;
        }
        d2l[ql][s * 64 + rloc] = d2;
    }
    __syncthreads();                            // cross-wave d2 visibility

    // ---- per-wave top-32 for query `wid` (identical to R6)
    ull sk[16];
    #pragma unroll
    for (int j = 0; j < 16; ++j) {
        float d2 = d2l[wid][j * 64 + lane];
        sk[j] = ((ull)__float_as_uint(d2) << 10) | (unsigned)(j * 64 + lane);
    }

    #pragma unroll
    for (int k = 2; k <= 16; k <<= 1) {
        #pragma unroll
        for (int j = k >> 1; j > 0; j >>= 1) {
            #pragma unroll
            for (int i = 0; i < 16; ++i) {
                int ixj = i ^ j;
                if (ixj > i) {
                    if ((i & k) == 0) {
                        ull a_ = sk[i], b_ = sk[ixj];
                        bool c_ = b_ < a_;
                        sk[i] = c_ ? b_ : a_; sk[ixj] = c_ ? a_ : b_;
                    } else {
                        ull a_ = sk[i], b_ = sk[ixj];
                        bool c_ = a_ < b_;
                        sk[i] = c_ ? b_ : a_; sk[ixj] = c_ ? a_ : b_;
                    }
                }
            }
        }
    }

    ull lkey = sk[0];
    for (int it = 0; it < KSEL; ++it) {
        ull m = lkey;
        #pragma unroll
        for (int off = 1; off < 64; off <<= 1) {
            ull o = __shfl_xor(m, off);
            m = o < m ? o : m;
        }
        if (lane == it) win_l[wid][it] = m;
        if (lkey == m) {                        // unique winner lane
            #pragma unroll
            for (int j = 0; j < 15; ++j) sk[j] = sk[j + 1];
            sk[15] = ~0ull;
            lkey = sk[0];
        }
    }

    if (lane < KSEL) {
        ull m = win_l[wid][lane];
        unsigned gidx = (unsigned)(sc * CHUNK) + (unsigned)(m & 1023u);
        float lab = labels[gidx];
        ull* dst = cand + ((size_t)(qg * QG + wid) * NCH + sc) * KSEL;
        dst[lane] = ((ull)(unsigned)(m >> 10) << 32) | (ull)__float_as_uint(lab);
    }
}

// ---------------------------------------------------------------------------
// Phase B: unchanged (absmax 0). Wave per query; lanes 0..15 merge the 16
// sorted chunk lists; labels ride in the candidate payload.
__global__ __launch_bounds__(256) void knn_phaseB(
    const ull* __restrict__ cand, float* __restrict__ out)
{
    const int lane = threadIdx.x & 63;
    const int wid  = threadIdx.x >> 6;
    const int q    = blockIdx.x * 4 + wid;

    const bool act = lane < NCH;
    const ull* lst = cand + ((size_t)q * NCH + (lane & 15)) * KSEL;
    int ptr = 0;
    ull cur = act ? lst[0] : ~0ull;

    float d0 = 0.0f, sw = 0.0f, sl = 0.0f;
    for (int it = 0; it < KSEL; ++it) {
        unsigned mv = (unsigned)(cur >> 32);
        unsigned ml = (unsigned)cur;
        #pragma unroll
        for (int off = 1; off < 16; off <<= 1) {
            unsigned ov = __shfl_xor(mv, off);
            unsigned ol = __shfl_xor(ml, off);
            bool take = (ov < mv) || (ov == mv && (lane & off));
            mv = take ? ov : mv;
            ml = take ? ol : ml;
        }
        ull b = __ballot(act && (unsigned)(cur >> 32) == mv);
        int wl = (int)(__ffsll((long long)b) - 1);
        if (lane == wl) {
            ++ptr;
            cur = (ptr < KSEL) ? lst[ptr] : ~0ull;
        }
        if (lane == 0) {
            float d = sqrtf(__uint_as_float(mv));
            if (it == 0) d0 = d;
            float w = expf((d0 - d) * INV_T);
            sw += w;
            sl += w * __uint_as_float(ml);
        }
    }
    if (lane == 0) out[q] = sl / sw;
}

// ---------------------------------------------------------------------------
extern "C" void kernel_launch(void* const* d_in, const int* in_sizes, int n_in,
                              void* d_out, int out_size, void* d_ws, size_t ws_size,
                              hipStream_t stream) {
    const float* x      = (const float*)d_in[0];   // [256,256]
    const float* sx     = (const float*)d_in[1];   // [16384,256]
    const float* labels = (const float*)d_in[2];   // [16384,1]
    const float* W1     = (const float*)d_in[3];   // [64,256]
    const float* b1     = (const float*)d_in[4];
    const float* W2     = (const float*)d_in[5];   // [64,64]
    const float* b2     = (const float*)d_in[6];
    const float* W3     = (const float*)d_in[7];   // [64,64]
    const float* b3     = (const float*)d_in[8];
    float* out = (float*)d_out;

    float* ws     = (float*)d_ws;
    float* s_emb  = ws;                            // 16384*64
    float* s_norm = s_emb + N_SUP * D_E;           // 16384
    float* q_emb  = s_norm + N_SUP;                // 256*64
    float* q_norm = q_emb + NQ * D_E;              // 256
    float* W1T    = q_norm + NQ;                   // 256*64
    float* W2T    = W1T + D_IN * D_E;              // 64*64
    float* W3T    = W2T + D_E * D_E;               // 64*64
    ull*   cand   = (ull*)(W3T + D_E * D_E);       // 256*16*32 ull

    prep_w<<<32, 256, 0, stream>>>(W1, W2, W3, W1T, W2T, W3T);
    embed_kernel<<<(N_SUP + NQ) / 64, 512, 0, stream>>>(
        sx, x, W1T, b1, W2T, b2, W3T, b3, s_emb, s_norm, q_emb, q_norm);
    knn_phaseA<<<NQG * NCH, 512, 0, stream>>>(s_emb, s_norm, q_emb, q_norm,
                                              labels, cand);
    knn_phaseB<<<NQ / 4, 256, 0, stream>>>(cand, out);
}

// Round 9
// 111.498 us; speedup vs baseline: 2.0066x; 1.3639x over previous
//
#include <hip/hip_runtime.h>
#include <math.h>

#define D_IN   256
#define D_E    64
#define N_SUP  16384
#define NQ     256
#define KSEL   32
#define RTOLC  1e-5f
#define ATOLC  1e-5f
#define INV_T  10.0f    // 1/TEMPERATURE

#define CHUNK  1024     // support rows per phase-A block
#define NCH    16       // support chunks
#define QG     8        // queries per phase-A block (= waves)
#define NQG    32       // query groups
#define EROWS  16       // rows per embed block -> 1040 blocks (grid was the wall)

typedef unsigned long long ull;

__device__ __forceinline__ float gelu_exact(float x) {
    return 0.5f * x * (1.0f + erff(x * 0.70710678118654752440f));
}

// ---------------------------------------------------------------------------
// Embed: 1040 blocks x 256 threads (4 waves). 16 rows/block; thread = (row
// r = tid&15, feature-group fg = tid>>4, f = 4*fg). Per k: 1 LDS x-read
// (16-addr broadcast) + 1 LDS W b128 (4 distinct/wave) + 4 FMA. x and W
// chunks double-buffered in LDS; W transposed during staging (no prep
// kernel). 49 KB LDS -> 3 blocks/CU = 12 waves/CU. FMA chain per (row,f)
// is k-ascending: same numerics as R5-R8.
__global__ __launch_bounds__(256, 4) void embed_kernel(
    const float* __restrict__ sx, const float* __restrict__ x,
    const float* __restrict__ W1, const float* __restrict__ b1,
    const float* __restrict__ W2, const float* __restrict__ b2,
    const float* __restrict__ W3, const float* __restrict__ b3,
    float* __restrict__ s_emb, float* __restrict__ s_norm,
    float* __restrict__ q_emb, float* __restrict__ q_norm)
{
    __shared__ float xc[2][64][17];   // x chunk [k][r]; xc[0] reused as hB [f][r]
    __shared__ float wc[2][64][68];   // W chunk transposed [k][f]
    __shared__ float hA[64][17];      // layer-1 out [f][r]
    __shared__ float nsq[16][17];     // [r][fg] norm partials

    const int tid = threadIdx.x;
    const int r   = tid & 15;
    const int fg4 = (tid >> 4) * 4;
    const bool isq = blockIdx.x >= (N_SUP / EROWS);
    const float* src = isq ? (x + (size_t)(blockIdx.x - N_SUP / EROWS) * EROWS * D_IN)
                           : (sx + (size_t)blockIdx.x * EROWS * D_IN);

    // stage x chunk kc into xc[b] (coalesced; transposed write)
    #define STAGE_X(kc_, b_)                                                   \
        {                                                                      \
            int row_ = tid >> 4, c4_ = tid & 15;                               \
            float4 v_ = *reinterpret_cast<const float4*>(                      \
                src + (size_t)row_ * D_IN + (kc_) * 64 + c4_ * 4);             \
            xc[b_][c4_ * 4 + 0][row_] = v_.x;                                  \
            xc[b_][c4_ * 4 + 1][row_] = v_.y;                                  \
            xc[b_][c4_ * 4 + 2][row_] = v_.z;                                  \
            xc[b_][c4_ * 4 + 3][row_] = v_.w;                                  \
        }
    // stage W1 chunk kc transposed into wc[b]: wc[k][f] = W1[f][kc*64+k]
    #define STAGE_W1(kc_, b_)                                                  \
        {                                                                      \
            _Pragma("unroll")                                                  \
            for (int i_ = 0; i_ < 4; ++i_) {                                   \
                int g_ = i_ * 256 + tid;                                       \
                int f_ = g_ >> 4, c4_ = g_ & 15;                               \
                float4 w_ = *reinterpret_cast<const float4*>(                  \
                    W1 + (size_t)f_ * D_IN + (kc_) * 64 + c4_ * 4);            \
                wc[b_][c4_ * 4 + 0][f_] = w_.x;                                \
                wc[b_][c4_ * 4 + 1][f_] = w_.y;                                \
                wc[b_][c4_ * 4 + 2][f_] = w_.z;                                \
                wc[b_][c4_ * 4 + 3][f_] = w_.w;                                \
            }                                                                  \
        }

    STAGE_X(0, 0);
    STAGE_W1(0, 0);
    __syncthreads();

    // ---- layer 1: 4 k-chunks of 64, k ascending
    float4 bv1 = *reinterpret_cast<const float4*>(b1 + fg4);
    float acc[4] = {bv1.x, bv1.y, bv1.z, bv1.w};
    for (int kc = 0; kc < 4; ++kc) {
        const int b = kc & 1;
        if (kc < 3) { STAGE_X(kc + 1, b ^ 1); STAGE_W1(kc + 1, b ^ 1); }
        #pragma unroll 8
        for (int k = 0; k < 64; ++k) {
            float xk = xc[b][k][r];
            float4 wv = *reinterpret_cast<const float4*>(&wc[b][k][fg4]);
            acc[0] = fmaf(wv.x, xk, acc[0]);
            acc[1] = fmaf(wv.y, xk, acc[1]);
            acc[2] = fmaf(wv.z, xk, acc[2]);
            acc[3] = fmaf(wv.w, xk, acc[3]);
        }
        __syncthreads();
    }
    // hA + stage W2 -> wc[0], W3 -> wc[1] (transposed)
    #pragma unroll
    for (int i = 0; i < 4; ++i) hA[fg4 + i][r] = gelu_exact(acc[i]);
    #pragma unroll
    for (int i = 0; i < 4; ++i) {
        int g = i * 256 + tid;
        int f = g >> 4, c4 = g & 15;
        float4 w2 = *reinterpret_cast<const float4*>(W2 + (size_t)f * D_E + c4 * 4);
        wc[0][c4 * 4 + 0][f] = w2.x; wc[0][c4 * 4 + 1][f] = w2.y;
        wc[0][c4 * 4 + 2][f] = w2.z; wc[0][c4 * 4 + 3][f] = w2.w;
        float4 w3 = *reinterpret_cast<const float4*>(W3 + (size_t)f * D_E + c4 * 4);
        wc[1][c4 * 4 + 0][f] = w3.x; wc[1][c4 * 4 + 1][f] = w3.y;
        wc[1][c4 * 4 + 2][f] = w3.z; wc[1][c4 * 4 + 3][f] = w3.w;
    }
    __syncthreads();

    // ---- layer 2 (reads hA + wc[0]; writes hB into xc[0])
    float4 bv2 = *reinterpret_cast<const float4*>(b2 + fg4);
    float a2[4] = {bv2.x, bv2.y, bv2.z, bv2.w};
    #pragma unroll 8
    for (int k = 0; k < D_E; ++k) {
        float hk = hA[k][r];
        float4 wv = *reinterpret_cast<const float4*>(&wc[0][k][fg4]);
        a2[0] = fmaf(wv.x, hk, a2[0]);
        a2[1] = fmaf(wv.y, hk, a2[1]);
        a2[2] = fmaf(wv.z, hk, a2[2]);
        a2[3] = fmaf(wv.w, hk, a2[3]);
    }
    #pragma unroll
    for (int i = 0; i < 4; ++i) xc[0][fg4 + i][r] = gelu_exact(a2[i]);
    __syncthreads();

    // ---- layer 3 + sigmoid + norm
    float4 bv3 = *reinterpret_cast<const float4*>(b3 + fg4);
    float a3[4] = {bv3.x, bv3.y, bv3.z, bv3.w};
    #pragma unroll 8
    for (int k = 0; k < D_E; ++k) {
        float hk = xc[0][k][r];
        float4 wv = *reinterpret_cast<const float4*>(&wc[1][k][fg4]);
        a3[0] = fmaf(wv.x, hk, a3[0]);
        a3[1] = fmaf(wv.y, hk, a3[1]);
        a3[2] = fmaf(wv.z, hk, a3[2]);
        a3[3] = fmaf(wv.w, hk, a3[3]);
    }
    float e[4];
    float np = 0.0f;
    #pragma unroll
    for (int i = 0; i < 4; ++i) {
        e[i] = 1.0f / (1.0f + expf(-a3[i]));
        np = fmaf(e[i], e[i], np);
    }

    const int rowg = (isq ? (blockIdx.x - N_SUP / EROWS) * EROWS : blockIdx.x * EROWS) + r;
    float* E   = isq ? q_emb  : s_emb;
    float* Nrm = isq ? q_norm : s_norm;
    *reinterpret_cast<float4*>(E + (size_t)rowg * D_E + fg4) =
        make_float4(e[0], e[1], e[2], e[3]);

    nsq[r][fg4 >> 2] = np;
    __syncthreads();
    if (tid < EROWS) {
        float s = nsq[tid][0];
        #pragma unroll
        for (int g = 1; g < 16; ++g) s += nsq[tid][g];
        const int rg = (isq ? (blockIdx.x - N_SUP / EROWS) * EROWS : blockIdx.x * EROWS) + tid;
        Nrm[rg] = s;
    }
    #undef STAGE_X
    #undef STAGE_W1
}

// ---------------------------------------------------------------------------
// Phase A: grid 512 = 2/CU exactly (qg = b>>4, sc = b&15), 512 threads.
// Queries in LDS (qs[8][68]: 8 b128 windows hit all 32 banks -> conflict-free
// broadcast; NO per-lane qv VGPR array -- that spilled in R7/R8). Tile
// double-buffered -> 1 barrier/stage. Lane (ql = lane>>3, rsub = lane&7) of
// wave w dots tile row w*8+rsub with query ql; k-ascending = same d2 bits.
// Selection: per-lane sort-16 (u64 keys), then 32 rounds of f32-bits
// wave-min (6 bpermutes) + ballot winner; exact row tie-break in a rare
// uniform branch. Matches (d2, index) lexicographic order exactly.
__global__ __launch_bounds__(512, 2) void knn_phaseA(
    const float* __restrict__ s_emb, const float* __restrict__ s_norm,
    const float* __restrict__ q_emb, const float* __restrict__ q_norm,
    const float* __restrict__ labels, ull* __restrict__ cand)
{
    __shared__ float tile[2][64 * 68];          // 34.8 KB
    __shared__ float d2l[QG][1032];             // 33 KB
    __shared__ float qs[QG][68];                // 2.2 KB
    __shared__ float qn_l[QG];
    __shared__ ull   win_l[QG][KSEL];           // 2 KB

    const int tid  = threadIdx.x;
    const int lane = tid & 63;
    const int wid  = tid >> 6;
    const int qg   = blockIdx.x >> 4;
    const int sc   = blockIdx.x & 15;

    // prologue: stage queries + first tile
    {
        int q = tid >> 6, c = tid & 63;
        qs[q][c] = q_emb[(size_t)(qg * QG + q) * D_E + c];
        if (tid < QG) qn_l[tid] = q_norm[qg * QG + tid];
        #pragma unroll
        for (int i = 0; i < 2; ++i) {
            int g = i * 512 + tid;
            int row = g >> 4, c4 = g & 15;
            float4 v = *reinterpret_cast<const float4*>(
                s_emb + (size_t)(sc * CHUNK + row) * D_E + c4 * 4);
            *reinterpret_cast<float4*>(&tile[0][row * 68 + c4 * 4]) = v;
        }
    }
    __syncthreads();

    const int ql   = lane >> 3;
    const int rsub = lane & 7;
    const int rloc = wid * 8 + rsub;
    const float qn = qn_l[ql];

    for (int s = 0; s < 16; ++s) {
        const int b = s & 1;
        if (s < 15) {
            #pragma unroll
            for (int i = 0; i < 2; ++i) {
                int g = i * 512 + tid;
                int row = g >> 4, c4 = g & 15;
                float4 v = *reinterpret_cast<const float4*>(
                    s_emb + (size_t)(sc * CHUNK + (s + 1) * 64 + row) * D_E + c4 * 4);
                *reinterpret_cast<float4*>(&tile[b ^ 1][row * 68 + c4 * 4]) = v;
            }
        }

        const float* tr = &tile[b][rloc * 68];
        const float* qp = &qs[ql][0];
        float a = 0.0f;
        #pragma unroll
        for (int c = 0; c < 16; ++c) {
            float4 sv = *reinterpret_cast<const float4*>(tr + c * 4);
            float4 qv = *reinterpret_cast<const float4*>(qp + c * 4);
            a = fmaf(qv.x, sv.x, a);
            a = fmaf(qv.y, sv.y, a);
            a = fmaf(qv.z, sv.z, a);
            a = fmaf(qv.w, sv.w, a);
        }
        const int grow = sc * CHUNK + s * 64 + rloc;
        float d2 = fmaxf(qn + s_norm[grow] - 2.0f * a, 0.0f);
        if (d2 < 1e-3f) {
            // possible isclose duplicate (true mask needs d2 <= 2.6e-8; fp32
            // error on d2 <= ~1e-5 -> 100x margin, ~never taken). All reads
            // from LDS: no register-array demotion possible.
            bool close = true;
            for (int k = 0; k < D_E; ++k) {
                float svk = tr[k];
                close = close && (fabsf(qs[ql][k] - svk) <= (ATOLC + RTOLC * fabsf(svk)));
            }
            if (close) d2 = INFINITY;
        }
        d2l[ql][s * 64 + rloc] = d2;
        __syncthreads();
    }

    // ---- per-wave top-32 for query `wid`
    ull sk[16];
    #pragma unroll
    for (int j = 0; j < 16; ++j) {
        float d2 = d2l[wid][j * 64 + lane];
        sk[j] = ((ull)__float_as_uint(d2) << 10) | (unsigned)(j * 64 + lane);
    }

    // bitonic sort 16 (ascending), static indices
    #pragma unroll
    for (int k = 2; k <= 16; k <<= 1) {
        #pragma unroll
        for (int j = k >> 1; j > 0; j >>= 1) {
            #pragma unroll
            for (int i = 0; i < 16; ++i) {
                int ixj = i ^ j;
                if (ixj > i) {
                    if ((i & k) == 0) {
                        ull a_ = sk[i], b_ = sk[ixj];
                        bool c_ = b_ < a_;
                        sk[i] = c_ ? b_ : a_; sk[ixj] = c_ ? a_ : b_;
                    } else {
                        ull a_ = sk[i], b_ = sk[ixj];
                        bool c_ = a_ < b_;
                        sk[i] = c_ ? b_ : a_; sk[ixj] = c_ ? a_ : b_;
                    }
                }
            }
        }
    }

    // 32 rounds: f32-bits wave-min + ballot winner (rare exact tie-break)
    ull lkey = sk[0];
    unsigned lv = (unsigned)(lkey >> 10);       // d2 bits (>=0: uint order = float order)
    for (int it = 0; it < KSEL; ++it) {
        unsigned m = lv;
        #pragma unroll
        for (int off = 1; off < 64; off <<= 1) {
            unsigned o = __shfl_xor(m, off);
            m = o < m ? o : m;
        }
        ull tb = __ballot(lv == m);
        if (__popcll(tb) > 1) {                 // rare: tie on d2 -> min row wins
            unsigned rr = (lv == m) ? (unsigned)(lkey & 1023u) : 0xffffffffu;
            unsigned rm = rr;
            #pragma unroll
            for (int off = 1; off < 64; off <<= 1) {
                unsigned o = __shfl_xor(rm, off);
                rm = o < rm ? o : rm;
            }
            tb = __ballot(rr == rm);
        }
        const int wl = (int)(__ffsll((long long)tb) - 1);
        if (lane == wl) {
            win_l[wid][it] = lkey;
            #pragma unroll
            for (int j = 0; j < 15; ++j) sk[j] = sk[j + 1];
            sk[15] = ~0ull;
            lkey = sk[0];
            lv = (unsigned)(lkey >> 10);
        }
    }

    // parallel label fetch + emit (sorted by (d2, idx))
    if (lane < KSEL) {
        ull m = win_l[wid][lane];
        unsigned gidx = (unsigned)(sc * CHUNK) + (unsigned)(m & 1023u);
        float lab = labels[gidx];
        ull* dst = cand + ((size_t)(qg * QG + wid) * NCH + sc) * KSEL;
        dst[lane] = ((ull)(unsigned)(m >> 10) << 32) | (ull)__float_as_uint(lab);
    }
}

// ---------------------------------------------------------------------------
// Phase B: unchanged (absmax 0). Wave per query; lanes 0..15 merge the 16
// sorted chunk lists; labels ride in the candidate payload.
__global__ __launch_bounds__(256) void knn_phaseB(
    const ull* __restrict__ cand, float* __restrict__ out)
{
    const int lane = threadIdx.x & 63;
    const int wid  = threadIdx.x >> 6;
    const int q    = blockIdx.x * 4 + wid;

    const bool act = lane < NCH;
    const ull* lst = cand + ((size_t)q * NCH + (lane & 15)) * KSEL;
    int ptr = 0;
    ull cur = act ? lst[0] : ~0ull;

    float d0 = 0.0f, sw = 0.0f, sl = 0.0f;
    for (int it = 0; it < KSEL; ++it) {
        unsigned mv = (unsigned)(cur >> 32);
        unsigned ml = (unsigned)cur;
        #pragma unroll
        for (int off = 1; off < 16; off <<= 1) {
            unsigned ov = __shfl_xor(mv, off);
            unsigned ol = __shfl_xor(ml, off);
            bool take = (ov < mv) || (ov == mv && (lane & off));
            mv = take ? ov : mv;
            ml = take ? ol : ml;
        }
        ull b = __ballot(act && (unsigned)(cur >> 32) == mv);
        int wl = (int)(__ffsll((long long)b) - 1);
        if (lane == wl) {
            ++ptr;
            cur = (ptr < KSEL) ? lst[ptr] : ~0ull;
        }
        if (lane == 0) {
            float d = sqrtf(__uint_as_float(mv));
            if (it == 0) d0 = d;
            float w = expf((d0 - d) * INV_T);
            sw += w;
            sl += w * __uint_as_float(ml);
        }
    }
    if (lane == 0) out[q] = sl / sw;
}

// ---------------------------------------------------------------------------
extern "C" void kernel_launch(void* const* d_in, const int* in_sizes, int n_in,
                              void* d_out, int out_size, void* d_ws, size_t ws_size,
                              hipStream_t stream) {
    const float* x      = (const float*)d_in[0];   // [256,256]
    const float* sx     = (const float*)d_in[1];   // [16384,256]
    const float* labels = (const float*)d_in[2];   // [16384,1]
    const float* W1     = (const float*)d_in[3];   // [64,256]
    const float* b1     = (const float*)d_in[4];
    const float* W2     = (const float*)d_in[5];   // [64,64]
    const float* b2     = (const float*)d_in[6];
    const float* W3     = (const float*)d_in[7];   // [64,64]
    const float* b3     = (const float*)d_in[8];
    float* out = (float*)d_out;

    float* ws     = (float*)d_ws;
    float* s_emb  = ws;                            // 16384*64
    float* s_norm = s_emb + N_SUP * D_E;           // 16384
    float* q_emb  = s_norm + N_SUP;                // 256*64
    float* q_norm = q_emb + NQ * D_E;              // 256
    ull*   cand   = (ull*)(q_norm + NQ);           // 256*16*32 ull (8B aligned)

    embed_kernel<<<(N_SUP + NQ) / EROWS, 256, 0, stream>>>(
        sx, x, W1, b1, W2, b2, W3, b3, s_emb, s_norm, q_emb, q_norm);
    knn_phaseA<<<NQG * NCH, 512, 0, stream>>>(s_emb, s_norm, q_emb, q_norm,
                                              labels, cand);
    knn_phaseB<<<NQ / 4, 256, 0, stream>>>(cand, out);
}